// Round 10
// baseline (73.310 us; speedup 1.0000x reference)
//
#include <hip/hip_runtime.h>

#define V_DIM 128000
#define NV4 (V_DIM / 4)             // 32000
#define K_TOP 50
#define BLK 1024
#define NWAVE (BLK / 64)            // 16
#define CAP 1024                    // candidate cap (E[n]=173, sigma~13)
#define NBINS 2048
#define THRESH 3.0f                 // P(N(0,1)>3)=1.35e-3 -> E[n]=173 >> 50
#define GRP (BLK * 4)               // 4096 float4 per depth-4 group
#define NFULL ((NV4 / GRP) * GRP)   // 28672

typedef float floatx4 __attribute__((ext_vector_type(4)));

__device__ __forceinline__ unsigned key_of(float x) {
    unsigned b = __float_as_uint(x);
    return b ^ (unsigned)((((int)b) >> 31) | 0x80000000);
}
__device__ __forceinline__ float val_of(unsigned u) {
    unsigned b = u ^ (unsigned)(((~(int)u) >> 31) | 0x80000000);
    return __uint_as_float(b);
}

// pass-2 body: masked softmax write for one float4 (USE_F hoisted to template)
template <bool USE_F>
__device__ __forceinline__ void wr4(const float4 v, int j, float thrv, unsigned thr,
                                    int idxcut, float lnS, floatx4* __restrict__ o4) {
    const int i0 = 4 * j;
    bool m0, m1, m2, m3;
    if (USE_F) {
        m0 = (v.x > thrv) || (v.x == thrv && i0 <= idxcut);
        m1 = (v.y > thrv) || (v.y == thrv && i0 + 1 <= idxcut);
        m2 = (v.z > thrv) || (v.z == thrv && i0 + 2 <= idxcut);
        m3 = (v.w > thrv) || (v.w == thrv && i0 + 3 <= idxcut);
    } else {
        unsigned u0 = key_of(v.x), u1 = key_of(v.y), u2 = key_of(v.z), u3 = key_of(v.w);
        m0 = (u0 > thr) || (u0 == thr && i0 <= idxcut);
        m1 = (u1 > thr) || (u1 == thr && i0 + 1 <= idxcut);
        m2 = (u2 > thr) || (u2 == thr && i0 + 2 <= idxcut);
        m3 = (u3 > thr) || (u3 == thr && i0 + 3 <= idxcut);
    }
    floatx4 o;
    o.x = m0 ? 0.f : __expf(v.x - lnS);
    o.y = m1 ? 0.f : __expf(v.y - lnS);
    o.z = m2 ? 0.f : __expf(v.z - lnS);
    o.w = m3 ? 0.f : __expf(v.w - lnS);
    __builtin_nontemporal_store(o, &o4[j]);   // keep input L3-resident
}

// depth-2 pipelined pass 2: ONE contiguous store stream (proven 128 MB write)
template <bool USE_F>
__device__ __forceinline__ void pass2(const float4* __restrict__ x4,
                                      floatx4* __restrict__ o4, int t,
                                      float thrv, unsigned thr, int idxcut, float lnS) {
    int j = t;
    float4 cur = x4[j];
    for (; j + BLK < NV4; j += BLK) {
        float4 nxt = x4[j + BLK];         // in flight while cur is processed
        wr4<USE_F>(cur, j, thrv, thr, idxcut, lnS, o4);
        cur = nxt;
    }
    wr4<USE_F>(cur, j, thrv, thr, idxcut, lnS, o4);
}

__global__ __launch_bounds__(BLK, 1)
void topk_softmax_fused(const float* __restrict__ x, float* __restrict__ out) {
    __shared__ unsigned cu_[CAP];
    __shared__ unsigned ci_[CAP];
    __shared__ unsigned hist[NBINS];    // fallback only
    __shared__ double   wsum[NWAVE];
    __shared__ double   msum[NWAVE];
    __shared__ unsigned s_cnt, s_thr, s_b1;
    __shared__ int      s_e, s_idxcut;
    __shared__ float    s_lnS;

    const int t = threadIdx.x;
    const int row = blockIdx.x;
    const float4* __restrict__ x4 = (const float4*)(x + (size_t)row * V_DIM);

    if (t == 0) s_cnt = 0;
    __syncthreads();

#define PUSH(val, idx) { unsigned p = atomicAdd(&s_cnt, 1u); if (p < CAP) { cu_[p] = key_of(val); ci_[p] = (unsigned)(idx); } }
#define COLL(v, jb) { \
        float mx_ = fmaxf(fmaxf(v.x, v.y), fmaxf(v.z, v.w)); \
        if (mx_ > THRESH) { \
            if (v.x > THRESH) PUSH(v.x, 4 * (jb)); \
            if (v.y > THRESH) PUSH(v.y, 4 * (jb) + 1); \
            if (v.z > THRESH) PUSH(v.z, 4 * (jb) + 2); \
            if (v.w > THRESH) PUSH(v.w, 4 * (jb) + 3); } }

    // ---- pass 1 (depth-4 load streams): exp partials + collect candidates ----
    float ls0 = 0.f, ls1 = 0.f, ls2 = 0.f, ls3 = 0.f;
    for (int jj = 0; jj < NFULL; jj += GRP) {
        const int j0 = jj + t;
        float4 a = x4[j0];
        float4 b = x4[j0 + BLK];
        float4 c = x4[j0 + 2 * BLK];
        float4 d = x4[j0 + 3 * BLK];
        ls0 += __expf(a.x) + __expf(a.y) + __expf(a.z) + __expf(a.w);
        COLL(a, j0);
        ls1 += __expf(b.x) + __expf(b.y) + __expf(b.z) + __expf(b.w);
        COLL(b, j0 + BLK);
        ls2 += __expf(c.x) + __expf(c.y) + __expf(c.z) + __expf(c.w);
        COLL(c, j0 + 2 * BLK);
        ls3 += __expf(d.x) + __expf(d.y) + __expf(d.z) + __expf(d.w);
        COLL(d, j0 + 3 * BLK);
    }
    for (int j = NFULL + t; j < NV4; j += BLK) {   // tail 3328 float4
        float4 a = x4[j];
        ls0 += __expf(a.x) + __expf(a.y) + __expf(a.z) + __expf(a.w);
        COLL(a, j);
    }
    float lsum = (ls0 + ls1) + (ls2 + ls3);        // fixed order -> deterministic
    #pragma unroll
    for (int off = 32; off; off >>= 1) lsum += __shfl_down(lsum, off);
    if ((t & 63) == 0) wsum[t >> 6] = (double)lsum;
    __syncthreads();
    unsigned n = s_cnt;

    if (n < (unsigned)K_TOP || n > (unsigned)CAP) {
        // ---- exact fallback (never taken for N(0,1)): full-row histogram select ----
        for (int i = t; i < NBINS; i += BLK) hist[i] = 0;
        if (t == 0) s_cnt = 0;
        __syncthreads();
        for (int j = t; j < NV4; j += BLK) {
            float4 v = x4[j];
            atomicAdd(&hist[key_of(v.x) >> 21], 1u);
            atomicAdd(&hist[key_of(v.y) >> 21], 1u);
            atomicAdd(&hist[key_of(v.z) >> 21], 1u);
            atomicAdd(&hist[key_of(v.w) >> 21], 1u);
        }
        __syncthreads();
        if (t == 0) {
            unsigned cum = 0; int b1 = 0;
            for (int b = NBINS - 1; b >= 0; --b) {
                if (cum + hist[b] >= (unsigned)K_TOP) { b1 = b; break; }
                cum += hist[b];
            }
            s_b1 = (unsigned)b1;
        }
        __syncthreads();
        const unsigned kmin = s_b1 << 21;    // bins >= b1 contain the whole top-K
        for (int j = t; j < NV4; j += BLK) {
            float4 v = x4[j];
            unsigned u0 = key_of(v.x), u1 = key_of(v.y), u2 = key_of(v.z), u3 = key_of(v.w);
            if (u0 >= kmin) { unsigned p = atomicAdd(&s_cnt, 1u); if (p < CAP) { cu_[p] = u0; ci_[p] = 4u * j; } }
            if (u1 >= kmin) { unsigned p = atomicAdd(&s_cnt, 1u); if (p < CAP) { cu_[p] = u1; ci_[p] = 4u * j + 1u; } }
            if (u2 >= kmin) { unsigned p = atomicAdd(&s_cnt, 1u); if (p < CAP) { cu_[p] = u2; ci_[p] = 4u * j + 2u; } }
            if (u3 >= kmin) { unsigned p = atomicAdd(&s_cnt, 1u); if (p < CAP) { cu_[p] = u3; ci_[p] = 4u * j + 3u; } }
        }
        __syncthreads();
        n = (s_cnt < (unsigned)CAP) ? s_cnt : (unsigned)CAP;
    }
    __syncthreads();

    // ---- exact rank-K select among cu_[0..n) (contains all of top-K) ----
    for (int j = t; j < (int)n; j += BLK) {
        unsigned uj = cu_[j]; int g = 0, eq = 0;
        for (int k = 0; k < (int)n; ++k) {
            unsigned uk = cu_[k];
            g += (uk > uj) ? 1 : 0;
            eq += (uk == uj) ? 1 : 0;
        }
        if (g < K_TOP && K_TOP <= g + eq) { s_thr = uj; s_e = K_TOP - g; }
    }
    __syncthreads();
    const unsigned thr = s_thr; const int e = s_e;
    // e-th smallest index among ties (jax top_k masks lowest indices first)
    for (int j = t; j < (int)n; j += BLK) {
        if (cu_[j] == thr) {
            int ij = (int)ci_[j], rank = 0;
            for (int k = 0; k < (int)n; ++k)
                rank += (cu_[k] == thr && (int)ci_[k] < ij) ? 1 : 0;
            if (rank == e - 1) s_idxcut = ij;
        }
    }
    __syncthreads();
    const int idxcut = s_idxcut;
    // masked-sum (double) and S = sum(exp) - masked
    double ms = 0.0;
    for (int j = t; j < (int)n; j += BLK) {
        unsigned u = cu_[j];
        if (u > thr || (u == thr && (int)ci_[j] <= idxcut))
            ms += exp((double)val_of(u));
    }
    #pragma unroll
    for (int off = 32; off; off >>= 1) ms += __shfl_down(ms, off);
    if ((t & 63) == 0) msum[t >> 6] = ms;
    __syncthreads();
    if (t == 0) {
        double S = 0.0;
        for (int w = 0; w < NWAVE; ++w) S += wsum[w];   // fixed order
        for (int w = 0; w < NWAVE; ++w) S -= msum[w];
        s_lnS = (float)log(S);
    }
    __syncthreads();

    // ---- pass 2: masked softmax write (depth-2, single nt-store stream) ----
    const float lnS = s_lnS;
    const float thrv = val_of(thr);
    floatx4* __restrict__ o4 = (floatx4*)(out + (size_t)row * V_DIM);
    if (thrv != 0.0f) pass2<true>(x4, o4, t, thrv, thr, idxcut, lnS);
    else              pass2<false>(x4, o4, t, thrv, thr, idxcut, lnS);
}

extern "C" void kernel_launch(void* const* d_in, const int* in_sizes, int n_in,
                              void* d_out, int out_size, void* d_ws, size_t ws_size,
                              hipStream_t stream) {
    const float* scores = (const float*)d_in[0];
    float* out = (float*)d_out;
    const int B = in_sizes[0] / V_DIM;
    hipLaunchKernelGGL(topk_softmax_fused, dim3(B), dim3(BLK), 0, stream,
                       scores, out);
}

// Round 11
// 73.009 us; speedup vs baseline: 1.0041x; 1.0041x over previous
//
#include <hip/hip_runtime.h>

#define V_DIM 128000
#define NV4 (V_DIM / 4)             // 32000
#define K_TOP 50
#define BLK 1024
#define NWAVE (BLK / 64)            // 16
#define CAP 1024                    // candidate cap (E[n]=173, sigma~13)
#define NBINS 2048
#define THRESH 3.0f                 // P(N(0,1)>3)=1.35e-3 -> E[n]=173 >> 50

typedef float floatx4 __attribute__((ext_vector_type(4)));

__device__ __forceinline__ unsigned key_of(float x) {
    unsigned b = __float_as_uint(x);
    return b ^ (unsigned)((((int)b) >> 31) | 0x80000000);
}
__device__ __forceinline__ float val_of(unsigned u) {
    unsigned b = u ^ (unsigned)(((~(int)u) >> 31) | 0x80000000);
    return __uint_as_float(b);
}

// pass-2 body: masked softmax write for one float4 (USE_F hoisted to template)
template <bool USE_F>
__device__ __forceinline__ void wr4(const float4 v, int j, float thrv, unsigned thr,
                                    int idxcut, float lnS, floatx4* __restrict__ o4) {
    const int i0 = 4 * j;
    bool m0, m1, m2, m3;
    if (USE_F) {
        m0 = (v.x > thrv) || (v.x == thrv && i0 <= idxcut);
        m1 = (v.y > thrv) || (v.y == thrv && i0 + 1 <= idxcut);
        m2 = (v.z > thrv) || (v.z == thrv && i0 + 2 <= idxcut);
        m3 = (v.w > thrv) || (v.w == thrv && i0 + 3 <= idxcut);
    } else {
        unsigned u0 = key_of(v.x), u1 = key_of(v.y), u2 = key_of(v.z), u3 = key_of(v.w);
        m0 = (u0 > thr) || (u0 == thr && i0 <= idxcut);
        m1 = (u1 > thr) || (u1 == thr && i0 + 1 <= idxcut);
        m2 = (u2 > thr) || (u2 == thr && i0 + 2 <= idxcut);
        m3 = (u3 > thr) || (u3 == thr && i0 + 3 <= idxcut);
    }
    floatx4 o;
    o.x = m0 ? 0.f : __expf(v.x - lnS);
    o.y = m1 ? 0.f : __expf(v.y - lnS);
    o.z = m2 ? 0.f : __expf(v.z - lnS);
    o.w = m3 ? 0.f : __expf(v.w - lnS);
    o4[j] = o;                        // regular store (A/B vs R9's nontemporal)
}

// depth-2 pipelined pass 2: one contiguous store stream, next load issued early
template <bool USE_F>
__device__ __forceinline__ void pass2(const float4* __restrict__ x4,
                                      floatx4* __restrict__ o4, int t,
                                      float thrv, unsigned thr, int idxcut, float lnS) {
    int j = t;
    float4 cur = x4[j];
    for (; j + BLK < NV4; j += BLK) {
        float4 nxt = x4[j + BLK];         // in flight while cur is processed
        wr4<USE_F>(cur, j, thrv, thr, idxcut, lnS, o4);
        cur = nxt;
    }
    wr4<USE_F>(cur, j, thrv, thr, idxcut, lnS, o4);
}

__global__ __launch_bounds__(BLK, 1)
void topk_softmax_fused(const float* __restrict__ x, float* __restrict__ out) {
    __shared__ unsigned cu_[CAP];
    __shared__ unsigned ci_[CAP];
    __shared__ unsigned hist[NBINS];    // fallback only
    __shared__ double   wsum[NWAVE];
    __shared__ double   msum[NWAVE];
    __shared__ unsigned s_cnt, s_thr, s_b1;
    __shared__ int      s_e, s_idxcut;
    __shared__ float    s_lnS;

    const int t = threadIdx.x;
    const int row = blockIdx.x;
    const float4* __restrict__ x4 = (const float4*)(x + (size_t)row * V_DIM);

    if (t == 0) s_cnt = 0;
    __syncthreads();

#define PUSH(val, idx) { unsigned p = atomicAdd(&s_cnt, 1u); if (p < CAP) { cu_[p] = key_of(val); ci_[p] = (unsigned)(idx); } }
#define COLL(v, jb) { \
        if (v.x > THRESH) PUSH(v.x, 4 * (jb)); \
        if (v.y > THRESH) PUSH(v.y, 4 * (jb) + 1); \
        if (v.z > THRESH) PUSH(v.z, 4 * (jb) + 2); \
        if (v.w > THRESH) PUSH(v.w, 4 * (jb) + 3); }
#define PROC1(v, jb) { \
        ls0 += __expf(v.x) + __expf(v.y); \
        ls1 += __expf(v.z) + __expf(v.w); \
        COLL(v, jb); }

    // ---- pass 1 (depth-2 pipelined): exp partial + collect candidates > THRESH ----
    float ls0 = 0.f, ls1 = 0.f;
    {
        int j = t;
        float4 cur = x4[j];
        for (; j + BLK < NV4; j += BLK) {
            float4 nxt = x4[j + BLK];     // in flight while cur is processed
            PROC1(cur, j);
            cur = nxt;
        }
        PROC1(cur, j);
    }
    float lsum = ls0 + ls1;
    #pragma unroll
    for (int off = 32; off; off >>= 1) lsum += __shfl_down(lsum, off);
    if ((t & 63) == 0) wsum[t >> 6] = (double)lsum;   // fixed slots -> deterministic
    __syncthreads();
    unsigned n = s_cnt;

    if (n < (unsigned)K_TOP || n > (unsigned)CAP) {
        // ---- exact fallback (never taken for N(0,1)): full-row histogram select ----
        for (int i = t; i < NBINS; i += BLK) hist[i] = 0;
        if (t == 0) s_cnt = 0;
        __syncthreads();
        for (int j = t; j < NV4; j += BLK) {
            float4 v = x4[j];
            atomicAdd(&hist[key_of(v.x) >> 21], 1u);
            atomicAdd(&hist[key_of(v.y) >> 21], 1u);
            atomicAdd(&hist[key_of(v.z) >> 21], 1u);
            atomicAdd(&hist[key_of(v.w) >> 21], 1u);
        }
        __syncthreads();
        if (t == 0) {
            unsigned cum = 0; int b1 = 0;
            for (int b = NBINS - 1; b >= 0; --b) {
                if (cum + hist[b] >= (unsigned)K_TOP) { b1 = b; break; }
                cum += hist[b];
            }
            s_b1 = (unsigned)b1;
        }
        __syncthreads();
        const unsigned kmin = s_b1 << 21;    // bins >= b1 contain the whole top-K
        for (int j = t; j < NV4; j += BLK) {
            float4 v = x4[j];
            unsigned u0 = key_of(v.x), u1 = key_of(v.y), u2 = key_of(v.z), u3 = key_of(v.w);
            if (u0 >= kmin) { unsigned p = atomicAdd(&s_cnt, 1u); if (p < CAP) { cu_[p] = u0; ci_[p] = 4u * j; } }
            if (u1 >= kmin) { unsigned p = atomicAdd(&s_cnt, 1u); if (p < CAP) { cu_[p] = u1; ci_[p] = 4u * j + 1u; } }
            if (u2 >= kmin) { unsigned p = atomicAdd(&s_cnt, 1u); if (p < CAP) { cu_[p] = u2; ci_[p] = 4u * j + 2u; } }
            if (u3 >= kmin) { unsigned p = atomicAdd(&s_cnt, 1u); if (p < CAP) { cu_[p] = u3; ci_[p] = 4u * j + 3u; } }
        }
        __syncthreads();
        n = (s_cnt < (unsigned)CAP) ? s_cnt : (unsigned)CAP;
    }
    __syncthreads();

    // ---- exact rank-K select among cu_[0..n) (contains all of top-K) ----
    for (int j = t; j < (int)n; j += BLK) {
        unsigned uj = cu_[j]; int g = 0, eq = 0;
        for (int k = 0; k < (int)n; ++k) {
            unsigned uk = cu_[k];
            g += (uk > uj) ? 1 : 0;
            eq += (uk == uj) ? 1 : 0;
        }
        if (g < K_TOP && K_TOP <= g + eq) { s_thr = uj; s_e = K_TOP - g; }
    }
    __syncthreads();
    const unsigned thr = s_thr; const int e = s_e;
    // e-th smallest index among ties (jax top_k masks lowest indices first)
    for (int j = t; j < (int)n; j += BLK) {
        if (cu_[j] == thr) {
            int ij = (int)ci_[j], rank = 0;
            for (int k = 0; k < (int)n; ++k)
                rank += (cu_[k] == thr && (int)ci_[k] < ij) ? 1 : 0;
            if (rank == e - 1) s_idxcut = ij;
        }
    }
    __syncthreads();
    const int idxcut = s_idxcut;
    // masked-sum (double) and S = sum(exp) - masked
    double ms = 0.0;
    for (int j = t; j < (int)n; j += BLK) {
        unsigned u = cu_[j];
        if (u > thr || (u == thr && (int)ci_[j] <= idxcut))
            ms += exp((double)val_of(u));
    }
    #pragma unroll
    for (int off = 32; off; off >>= 1) ms += __shfl_down(ms, off);
    if ((t & 63) == 0) msum[t >> 6] = ms;
    __syncthreads();
    if (t == 0) {
        double S = 0.0;
        for (int w = 0; w < NWAVE; ++w) S += wsum[w];   // fixed order
        for (int w = 0; w < NWAVE; ++w) S -= msum[w];
        s_lnS = (float)log(S);
    }
    __syncthreads();

    // ---- pass 2: masked softmax write (depth-2, regular stores) ----
    const float lnS = s_lnS;
    const float thrv = val_of(thr);
    floatx4* __restrict__ o4 = (floatx4*)(out + (size_t)row * V_DIM);
    if (thrv != 0.0f) pass2<true>(x4, o4, t, thrv, thr, idxcut, lnS);
    else              pass2<false>(x4, o4, t, thrv, thr, idxcut, lnS);
}

extern "C" void kernel_launch(void* const* d_in, const int* in_sizes, int n_in,
                              void* d_out, int out_size, void* d_ws, size_t ws_size,
                              hipStream_t stream) {
    const float* scores = (const float*)d_in[0];
    float* out = (float*)d_out;
    const int B = in_sizes[0] / V_DIM;
    hipLaunchKernelGGL(topk_softmax_fused, dim3(B), dim3(BLK), 0, stream,
                       scores, out);
}

// Round 12
// 72.966 us; speedup vs baseline: 1.0047x; 1.0006x over previous
//
#include <hip/hip_runtime.h>

#define V_DIM 128000
#define NV4 (V_DIM / 4)             // 32000
#define K_TOP 50
#define BLK 1024
#define NWAVE (BLK / 64)            // 16
#define CAP 1024                    // candidate cap (E[n]=173, sigma~13)
#define NBINS 2048
#define THRESH 3.0f                 // P(N(0,1)>3)=1.35e-3 -> E[n]=173 >> 50
#define SEGS 32
#define SEGSZ 1000                  // float4 per segment; SEGS*SEGSZ == NV4

typedef float floatx4 __attribute__((ext_vector_type(4)));

__device__ __forceinline__ unsigned key_of(float x) {
    unsigned b = __float_as_uint(x);
    return b ^ (unsigned)((((int)b) >> 31) | 0x80000000);
}
__device__ __forceinline__ float val_of(unsigned u) {
    unsigned b = u ^ (unsigned)(((~(int)u) >> 31) | 0x80000000);
    return __uint_as_float(b);
}

// pass-2 body: masked softmax write for one float4 (USE_F hoisted to template)
template <bool USE_F>
__device__ __forceinline__ void wr4(const float4 v, int j, float thrv, unsigned thr,
                                    int idxcut, float lnS, floatx4* __restrict__ o4) {
    const int i0 = 4 * j;
    bool m0, m1, m2, m3;
    if (USE_F) {
        m0 = (v.x > thrv) || (v.x == thrv && i0 <= idxcut);
        m1 = (v.y > thrv) || (v.y == thrv && i0 + 1 <= idxcut);
        m2 = (v.z > thrv) || (v.z == thrv && i0 + 2 <= idxcut);
        m3 = (v.w > thrv) || (v.w == thrv && i0 + 3 <= idxcut);
    } else {
        unsigned u0 = key_of(v.x), u1 = key_of(v.y), u2 = key_of(v.z), u3 = key_of(v.w);
        m0 = (u0 > thr) || (u0 == thr && i0 <= idxcut);
        m1 = (u1 > thr) || (u1 == thr && i0 + 1 <= idxcut);
        m2 = (u2 > thr) || (u2 == thr && i0 + 2 <= idxcut);
        m3 = (u3 > thr) || (u3 == thr && i0 + 3 <= idxcut);
    }
    floatx4 o;
    o.x = m0 ? 0.f : __expf(v.x - lnS);
    o.y = m1 ? 0.f : __expf(v.y - lnS);
    o.z = m2 ? 0.f : __expf(v.z - lnS);
    o.w = m3 ? 0.f : __expf(v.w - lnS);
    o4[j] = o;
}

// pass 2 with per-row segment rotation (channel decorrelation), depth-2 pipelined
template <bool USE_F>
__device__ __forceinline__ void pass2(const float4* __restrict__ x4,
                                      floatx4* __restrict__ o4, int t, int rot,
                                      float thrv, unsigned thr, int idxcut, float lnS) {
    if (t >= SEGSZ) return;
    int j = rot * SEGSZ + t;
    float4 cur = x4[j];
    for (int s = 1; s < SEGS; ++s) {
        const int jn = (((rot + s) & 31) * SEGSZ) + t;
        float4 nxt = x4[jn];              // in flight while cur is processed
        wr4<USE_F>(cur, j, thrv, thr, idxcut, lnS, o4);
        cur = nxt; j = jn;
    }
    wr4<USE_F>(cur, j, thrv, thr, idxcut, lnS, o4);
}

__global__ __launch_bounds__(BLK, 1)
void topk_softmax_fused(const float* __restrict__ x, float* __restrict__ out) {
    __shared__ unsigned cu_[CAP];
    __shared__ unsigned ci_[CAP];
    __shared__ unsigned hist[NBINS];    // fallback only
    __shared__ double   wsum[NWAVE];
    __shared__ double   msum[NWAVE];
    __shared__ unsigned s_cnt, s_thr, s_b1;
    __shared__ int      s_e, s_idxcut;
    __shared__ float    s_lnS;

    const int t = threadIdx.x;
    const int row = blockIdx.x;
    const int rot = (row * 7) & 31;     // per-row channel phase rotation
    const float4* __restrict__ x4 = (const float4*)(x + (size_t)row * V_DIM);

    if (t == 0) s_cnt = 0;
    __syncthreads();

#define PUSH(val, idx) { unsigned p = atomicAdd(&s_cnt, 1u); if (p < CAP) { cu_[p] = key_of(val); ci_[p] = (unsigned)(idx); } }
#define COLL(v, jb) { \
        if (v.x > THRESH) PUSH(v.x, 4 * (jb)); \
        if (v.y > THRESH) PUSH(v.y, 4 * (jb) + 1); \
        if (v.z > THRESH) PUSH(v.z, 4 * (jb) + 2); \
        if (v.w > THRESH) PUSH(v.w, 4 * (jb) + 3); }
#define PROC1(v, jb) { \
        ls0 += __expf(v.x) + __expf(v.y); \
        ls1 += __expf(v.z) + __expf(v.w); \
        COLL(v, jb); }

    // ---- pass 1: rotated segment order, depth-2 pipelined ----
    float ls0 = 0.f, ls1 = 0.f;
    if (t < SEGSZ) {
        int j = rot * SEGSZ + t;
        float4 cur = x4[j];
        for (int s = 1; s < SEGS; ++s) {
            const int jn = (((rot + s) & 31) * SEGSZ) + t;
            float4 nxt = x4[jn];          // in flight while cur is processed
            PROC1(cur, j);
            cur = nxt; j = jn;
        }
        PROC1(cur, j);
    }
    float lsum = ls0 + ls1;
    #pragma unroll
    for (int off = 32; off; off >>= 1) lsum += __shfl_down(lsum, off);
    if ((t & 63) == 0) wsum[t >> 6] = (double)lsum;   // fixed slots -> deterministic
    __syncthreads();
    unsigned n = s_cnt;

    if (n < (unsigned)K_TOP || n > (unsigned)CAP) {
        // ---- exact fallback (never taken for N(0,1)): full-row histogram select ----
        for (int i = t; i < NBINS; i += BLK) hist[i] = 0;
        if (t == 0) s_cnt = 0;
        __syncthreads();
        for (int j = t; j < NV4; j += BLK) {
            float4 v = x4[j];
            atomicAdd(&hist[key_of(v.x) >> 21], 1u);
            atomicAdd(&hist[key_of(v.y) >> 21], 1u);
            atomicAdd(&hist[key_of(v.z) >> 21], 1u);
            atomicAdd(&hist[key_of(v.w) >> 21], 1u);
        }
        __syncthreads();
        if (t == 0) {
            unsigned cum = 0; int b1 = 0;
            for (int b = NBINS - 1; b >= 0; --b) {
                if (cum + hist[b] >= (unsigned)K_TOP) { b1 = b; break; }
                cum += hist[b];
            }
            s_b1 = (unsigned)b1;
        }
        __syncthreads();
        const unsigned kmin = s_b1 << 21;    // bins >= b1 contain the whole top-K
        for (int j = t; j < NV4; j += BLK) {
            float4 v = x4[j];
            unsigned u0 = key_of(v.x), u1 = key_of(v.y), u2 = key_of(v.z), u3 = key_of(v.w);
            if (u0 >= kmin) { unsigned p = atomicAdd(&s_cnt, 1u); if (p < CAP) { cu_[p] = u0; ci_[p] = 4u * j; } }
            if (u1 >= kmin) { unsigned p = atomicAdd(&s_cnt, 1u); if (p < CAP) { cu_[p] = u1; ci_[p] = 4u * j + 1u; } }
            if (u2 >= kmin) { unsigned p = atomicAdd(&s_cnt, 1u); if (p < CAP) { cu_[p] = u2; ci_[p] = 4u * j + 2u; } }
            if (u3 >= kmin) { unsigned p = atomicAdd(&s_cnt, 1u); if (p < CAP) { cu_[p] = u3; ci_[p] = 4u * j + 3u; } }
        }
        __syncthreads();
        n = (s_cnt < (unsigned)CAP) ? s_cnt : (unsigned)CAP;
    }
    __syncthreads();

    // ---- exact rank-K select among cu_[0..n) (contains all of top-K) ----
    for (int j = t; j < (int)n; j += BLK) {
        unsigned uj = cu_[j]; int g = 0, eq = 0;
        for (int k = 0; k < (int)n; ++k) {
            unsigned uk = cu_[k];
            g += (uk > uj) ? 1 : 0;
            eq += (uk == uj) ? 1 : 0;
        }
        if (g < K_TOP && K_TOP <= g + eq) { s_thr = uj; s_e = K_TOP - g; }
    }
    __syncthreads();
    const unsigned thr = s_thr; const int e = s_e;
    // e-th smallest index among ties (jax top_k masks lowest indices first)
    for (int j = t; j < (int)n; j += BLK) {
        if (cu_[j] == thr) {
            int ij = (int)ci_[j], rank = 0;
            for (int k = 0; k < (int)n; ++k)
                rank += (cu_[k] == thr && (int)ci_[k] < ij) ? 1 : 0;
            if (rank == e - 1) s_idxcut = ij;
        }
    }
    __syncthreads();
    const int idxcut = s_idxcut;
    // masked-sum (double) and S = sum(exp) - masked
    double ms = 0.0;
    for (int j = t; j < (int)n; j += BLK) {
        unsigned u = cu_[j];
        if (u > thr || (u == thr && (int)ci_[j] <= idxcut))
            ms += exp((double)val_of(u));
    }
    #pragma unroll
    for (int off = 32; off; off >>= 1) ms += __shfl_down(ms, off);
    if ((t & 63) == 0) msum[t >> 6] = ms;
    __syncthreads();
    if (t == 0) {
        double S = 0.0;
        for (int w = 0; w < NWAVE; ++w) S += wsum[w];   // fixed order
        for (int w = 0; w < NWAVE; ++w) S -= msum[w];
        s_lnS = (float)log(S);
    }
    __syncthreads();

    // ---- pass 2: masked softmax write (rotated segments, depth-2) ----
    const float lnS = s_lnS;
    const float thrv = val_of(thr);
    floatx4* __restrict__ o4 = (floatx4*)(out + (size_t)row * V_DIM);
    if (thrv != 0.0f) pass2<true>(x4, o4, t, rot, thrv, thr, idxcut, lnS);
    else              pass2<false>(x4, o4, t, rot, thrv, thr, idxcut, lnS);
}

extern "C" void kernel_launch(void* const* d_in, const int* in_sizes, int n_in,
                              void* d_out, int out_size, void* d_ws, size_t ws_size,
                              hipStream_t stream) {
    const float* scores = (const float*)d_in[0];
    float* out = (float*)d_out;
    const int B = in_sizes[0] / V_DIM;
    hipLaunchKernelGGL(topk_softmax_fused, dim3(B), dim3(BLK), 0, stream,
                       scores, out);
}